// Round 8
// baseline (45.950 us; speedup 1.0000x reference)
//
#include <hip/hip_runtime.h>
#include <math.h>

// Problem constants (fixed by the reference setup)
#define NN 16
#define CC 85
#define HH 160
#define WW 160
#define HW_ 25600            // H*W
#define NHW 409600           // N*H*W
#define TB 256
#define CELLB 400            // K1 cell blocks: NHW/4/TB (one float4 per thread)
#define K2T 1024             // K2: single block, 16 waves on one CU

__device__ __forceinline__ float wave_sum(float v) {
#pragma unroll
  for (int o = 32; o; o >>= 1) v += __shfl_down(v, o, 64);
  return v;
}

__device__ __forceinline__ float sl1(float d) {
  float ad = fabsf(d);
  return (ad < 1.f) ? 0.5f * d * d : (ad - 0.5f);
}

// SIoU variant from the reference (_bbox_iou)
__device__ __forceinline__ float siou(float pcx, float pcy, float pw, float ph,
                                      float gcx, float gcy, float gw, float gh) {
  const float eps = 1e-7f;
  float b1x1 = pcx - pw * 0.5f, b1x2 = pcx + pw * 0.5f;
  float b1y1 = pcy - ph * 0.5f, b1y2 = pcy + ph * 0.5f;
  float b2x1 = gcx - gw * 0.5f, b2x2 = gcx + gw * 0.5f;
  float b2y1 = gcy - gh * 0.5f, b2y2 = gcy + gh * 0.5f;
  float inter = fmaxf(fminf(b1x2, b2x2) - fmaxf(b1x1, b2x1), 0.f) *
                fmaxf(fminf(b1y2, b2y2) - fmaxf(b1y1, b2y1), 0.f);
  float w1 = b1x2 - b1x1, h1 = b1y2 - b1y1 + eps;
  float w2 = b2x2 - b2x1, h2 = b2y2 - b2y1 + eps;
  float uni = w1 * h1 + w2 * h2 - inter + eps;
  float iou = inter / uni;
  float cw = fmaxf(b1x2, b2x2) - fminf(b1x1, b2x1);
  float ch = fmaxf(b1y2, b2y2) - fminf(b1y1, b2y1);
  float s_cw = (b2x1 + b2x2 - b1x1 - b1x2) * 0.5f;
  float s_ch = (b2y1 + b2y2 - b1y1 - b1y2) * 0.5f;
  float sigma = sqrtf(s_cw * s_cw + s_ch * s_ch);
  float sin_a1 = fabsf(s_cw) / sigma;
  float sin_a2 = fabsf(s_ch) / sigma;
  float sin_a = (sin_a1 > 0.70710678f) ? sin_a2 : sin_a1;
  // cos(2*asin(x) - pi/2) == 2*x*sqrt(1-x^2)
  float angle_cost = 2.f * sin_a * sqrtf(fmaxf(1.f - sin_a * sin_a, 0.f));
  float rx = s_cw / cw; rx *= rx;
  float ry = s_ch / ch; ry *= ry;
  float gamma = angle_cost - 2.f;
  float dist = 2.f - expf(gamma * rx) - expf(gamma * ry);
  float ow = fabsf(w1 - w2) / fmaxf(w1, w2);
  float oh = fabsf(h1 - h2) / fmaxf(h1, h2);
  float e1 = 1.f - expf(-ow), e2 = 1.f - expf(-oh);
  float s1 = e1 * e1; s1 *= s1;
  float s2 = e2 * e2; s2 *= s2;
  return iou - 0.5f * (dist + s1 + s2);
}

// K1: decoupled roles. Blocks [0,400): cell streaming only (base obj term).
// Blocks [400,400+nact): anchor gather + SIoU only. Critical path =
// max(cells, anchors), not sum. All results via per-block partials + a packed
// float4 per anchor; winner scatter-init covers exactly the cells K2 touches.
__global__ __launch_bounds__(TB)
void k1(const float* __restrict__ preds, const float* __restrict__ targets,
        int M, int* __restrict__ winner, float4* __restrict__ state4,
        float* __restrict__ partA_iou, float* __restrict__ partA_cnt,
        float* __restrict__ part_obj) {
  const int tid = threadIdx.x, bid = blockIdx.x;
  const int lane = tid & 63, wid = tid >> 6;
  __shared__ float sh0[4], sh1[4];

  if (bid < CELLB) {
    // ---- cells: one float4 per thread; tobj=0/factor=0.75 folded out ----
    int t = bid * TB + tid;
    int i0 = t * 4;
    int b = i0 / HW_;
    int r = i0 - b * HW_;                    // HW_ % 4 == 0
    float4 p4 = *reinterpret_cast<const float4*>(preds + (size_t)b * CC * HW_ + r);
    float objs = sl1(p4.x) + sl1(p4.y) + sl1(p4.z) + sl1(p4.w);
    float o = wave_sum(objs);
    if (lane == 0) sh0[wid] = o;
    __syncthreads();
    if (tid == 0) part_obj[bid] = sh0[0] + sh0[1] + sh0[2] + sh0[3];
  } else {
    // ---- anchors: decode + 6 gathers + SIoU + nll ----
    const int abid = bid - CELLB;
    const int t = abid * TB + tid;
    const int M4 = 4 * M;
    float iou_v = 0.f, mf = 0.f, pobj = 0.f, nllv = 0.f;
    int meta = 0;
    if (t < M4) {
      int mm = t % M, q = t / M;
      const float* t6 = targets + (size_t)mm * 6;
      int ab = (int)t6[0];
      int acls = (int)t6[1];
      float gx = t6[2] * (float)WW, gy = t6[3] * (float)HH;
      float gw = t6[4] * (float)WW, gh = t6[5] * (float)HH;
      int gi = (int)gx + (q & 1);
      int gj = (int)gy + (q >> 1);
      bool am = (gi >= 1) && (gi < WW) && (gj >= 1) && (gj < HH);
      if (am) {
        const float* p = preds + (size_t)ab * CC * HW_ + (size_t)gj * WW + gi;
        pobj = p[0];
        float p1 = p[(size_t)1 * HW_];
        float p2 = p[(size_t)2 * HW_];
        float p3 = p[(size_t)3 * HW_];
        float p4v = p[(size_t)4 * HW_];
        float pc = p[(size_t)(5 + acls) * HW_];
        float px = tanhf(p1) + (float)gi;
        float py = tanhf(p2) + (float)gj;
        float pw = (1.f / (1.f + expf(-p3))) * (float)WW;
        float ph = (1.f / (1.f + expf(-p4v))) * (float)HH;
        iou_v = siou(px, py, pw, ph, gx, gy, gw, gh);
        nllv = -logf(pc);
        mf = 1.f;
        int aidx = ab * HW_ + gj * WW + gi;
        winner[aidx] = -1;                   // scatter-init only cells used
        meta = 1 | (ab << 1) | (aidx << 5);  // aidx < 2^19 -> fits
      }
      state4[t] = make_float4(iou_v, pobj, nllv, __int_as_float(meta));
    }
    float s = wave_sum(iou_v), c = wave_sum(mf);
    if (lane == 0) { sh0[wid] = s; sh1[wid] = c; }
    __syncthreads();
    if (tid == 0) {
      partA_iou[abid] = sh0[0] + sh0[1] + sh0[2] + sh0[3];
      partA_cnt[abid] = sh1[0] + sh1[1] + sh1[2] + sh1[3];
    }
  }
}

// K2: SINGLE block, 1024 threads — every sync is a cheap __syncthreads on one
// CU; no agent-scope spin barriers, no global counters, no init state.
// Kernel boundary provides the grid barrier + cross-XCD visibility of K1's
// writes. winner atomicMax + re-read stay within this CU's XCD L2.
__global__ __launch_bounds__(K2T)
void k2(const float4* __restrict__ state4, int* __restrict__ winner,
        const float* __restrict__ partA_iou, const float* __restrict__ partA_cnt,
        const float* __restrict__ part_obj, int M, int nact,
        float* __restrict__ out) {
  const int tid = threadIdx.x;
  const int lane = tid & 63, wid = tid >> 6;   // 16 waves
  const int M4 = 4 * M;

  __shared__ float r0[16], r1[16], r2[16], r3[16];
  __shared__ int hist[NN];
  __shared__ float s_mean;
  __shared__ double s_base;
  if (tid < NN) hist[tid] = 0;

  // ---- iou_mean (64 anchor partials) + obj_base (400 cell partials) ----
  float si = 0.f, sc = 0.f, so = 0.f;
  for (int i = tid; i < nact; i += K2T) { si += partA_iou[i]; sc += partA_cnt[i]; }
  for (int i = tid; i < CELLB; i += K2T) so += part_obj[i];
  si = wave_sum(si); sc = wave_sum(sc); so = wave_sum(so);
  if (lane == 0) { r0[wid] = si; r1[wid] = sc; r2[wid] = so; }
  __syncthreads();          // also publishes hist zeroing
  if (tid == 0) {
    float a = 0.f, b = 0.f; double o = 0.0;
    for (int i = 0; i < 16; ++i) { a += r0[i]; b += r1[i]; o += (double)r2[i]; }
    s_mean = a / fmaxf(b, 1.f);
    s_base = o;
  }
  __syncthreads();
  const float iou_mean = s_mean;

  // ---- pass 1: filter, sums, nperb hist, winner last-wins ----
  float fc = 0.f, li = 0.f, nl = 0.f;
  for (int a = tid; a < M4; a += K2T) {
    float4 s4 = state4[a];
    int meta = __float_as_int(s4.w);
    if ((meta & 1) && s4.x > iou_mean) {
      fc += 1.f;
      li += 1.f - s4.x;
      nl += s4.z;
      atomicMax(&winner[meta >> 5], a);      // max-a == numpy last-wins
      atomicAdd(&hist[(meta >> 1) & 15], 1);
    }
  }
  fc = wave_sum(fc); li = wave_sum(li); nl = wave_sum(nl);
  if (lane == 0) { r0[wid] = fc; r1[wid] = li; r2[wid] = nl; }
  __syncthreads();   // drains atomics (vmcnt) -> winner/hist complete

  // ---- pass 2: winner-check correction (state4 now L1/L2-hot) ----
  float corr = 0.f;
  for (int a = tid; a < M4; a += K2T) {
    float4 s4 = state4[a];
    int meta = __float_as_int(s4.w);
    if ((meta & 1) && s4.x > iou_mean) {
      int w = __hip_atomic_load(&winner[meta >> 5], __ATOMIC_RELAXED,
                                __HIP_MEMORY_SCOPE_AGENT);  // L1-bypass
      if (w == a) {
        float fval = (float)HW_ / (float)hist[(meta >> 1) & 15] * 0.25f;
        corr += sl1(s4.y - s4.x) * fval - sl1(s4.y) * 0.75f;
      }
    }
  }
  corr = wave_sum(corr);
  if (lane == 0) r3[wid] = corr;
  __syncthreads();

  if (tid == 0) {
    float cf = 0.f, liou = 0.f, nll = 0.f; double co = 0.0;
    for (int i = 0; i < 16; ++i) {
      cf += r0[i]; liou += r1[i]; nll += r2[i]; co += (double)r3[i];
    }
    float cff = fmaxf(cf, 1.f);
    float iou_loss = liou / cff;
    float cls_loss = nll / cff;
    float obj_loss = (float)((0.75 * s_base + co) / (double)NHW);
    out[0] = iou_loss;
    out[1] = obj_loss;
    out[2] = cls_loss;
    out[3] = iou_loss * 8.f + obj_loss * 16.f + cls_loss;
  }
}

extern "C" void kernel_launch(void* const* d_in, const int* in_sizes, int n_in,
                              void* d_out, int out_size, void* d_ws, size_t ws_size,
                              hipStream_t stream) {
  const float* preds = (const float*)d_in[0];
  const float* targets = (const float*)d_in[1];
  int M = in_sizes[1] / 6;             // 4096
  int M4 = 4 * M;                      // 16384
  int nact = (M4 + TB - 1) / TB;       // 64 anchor blocks

  char* ws = (char*)d_ws;
  size_t off = 0;
  float4* state4 = (float4*)(ws + off);   off += (size_t)M4 * 16;       // 256 KB
  int* winner = (int*)(ws + off);         off += (size_t)NHW * 4;       // 1.6 MB
  float* partA_iou = (float*)(ws + off);  off += ((size_t)nact * 4 + 255) & ~(size_t)255;
  float* partA_cnt = (float*)(ws + off);  off += ((size_t)nact * 4 + 255) & ~(size_t)255;
  float* part_obj = (float*)(ws + off);   off += (size_t)CELLB * 4;

  k1<<<CELLB + nact, TB, 0, stream>>>(preds, targets, M, winner, state4,
                                      partA_iou, partA_cnt, part_obj);
  k2<<<1, K2T, 0, stream>>>(state4, winner, partA_iou, partA_cnt, part_obj,
                            M, nact, (float*)d_out);
}

// Round 9
// 29.966 us; speedup vs baseline: 1.5334x; 1.5334x over previous
//
#include <hip/hip_runtime.h>
#include <math.h>

// Problem constants (fixed by the reference setup)
#define NN 16
#define CC 85
#define HH 160
#define WW 160
#define HW_ 25600            // H*W
#define NHW 409600           // N*H*W
#define TB 256
#define CELLB 400            // K1 cell blocks: NHW/4/TB (one float4 per thread)
#define MAGICF 0x52554E31    // K2 block-done flag value

__device__ __forceinline__ float wave_sum(float v) {
#pragma unroll
  for (int o = 32; o; o >>= 1) v += __shfl_down(v, o, 64);
  return v;
}

__device__ __forceinline__ float sl1(float d) {
  float ad = fabsf(d);
  return (ad < 1.f) ? 0.5f * d * d : (ad - 0.5f);
}

// SIoU variant from the reference (_bbox_iou)
__device__ __forceinline__ float siou(float pcx, float pcy, float pw, float ph,
                                      float gcx, float gcy, float gw, float gh) {
  const float eps = 1e-7f;
  float b1x1 = pcx - pw * 0.5f, b1x2 = pcx + pw * 0.5f;
  float b1y1 = pcy - ph * 0.5f, b1y2 = pcy + ph * 0.5f;
  float b2x1 = gcx - gw * 0.5f, b2x2 = gcx + gw * 0.5f;
  float b2y1 = gcy - gh * 0.5f, b2y2 = gcy + gh * 0.5f;
  float inter = fmaxf(fminf(b1x2, b2x2) - fmaxf(b1x1, b2x1), 0.f) *
                fmaxf(fminf(b1y2, b2y2) - fmaxf(b1y1, b2y1), 0.f);
  float w1 = b1x2 - b1x1, h1 = b1y2 - b1y1 + eps;
  float w2 = b2x2 - b2x1, h2 = b2y2 - b2y1 + eps;
  float uni = w1 * h1 + w2 * h2 - inter + eps;
  float iou = inter / uni;
  float cw = fmaxf(b1x2, b2x2) - fminf(b1x1, b2x1);
  float ch = fmaxf(b1y2, b2y2) - fminf(b1y1, b2y1);
  float s_cw = (b2x1 + b2x2 - b1x1 - b1x2) * 0.5f;
  float s_ch = (b2y1 + b2y2 - b1y1 - b1y2) * 0.5f;
  float sigma = sqrtf(s_cw * s_cw + s_ch * s_ch);
  float sin_a1 = fabsf(s_cw) / sigma;
  float sin_a2 = fabsf(s_ch) / sigma;
  float sin_a = (sin_a1 > 0.70710678f) ? sin_a2 : sin_a1;
  // cos(2*asin(x) - pi/2) == 2*x*sqrt(1-x^2)
  float angle_cost = 2.f * sin_a * sqrtf(fmaxf(1.f - sin_a * sin_a, 0.f));
  float rx = s_cw / cw; rx *= rx;
  float ry = s_ch / ch; ry *= ry;
  float gamma = angle_cost - 2.f;
  float dist = 2.f - expf(gamma * rx) - expf(gamma * ry);
  float ow = fabsf(w1 - w2) / fmaxf(w1, w2);
  float oh = fabsf(h1 - h2) / fmaxf(h1, h2);
  float e1 = 1.f - expf(-ow), e2 = 1.f - expf(-oh);
  float s1 = e1 * e1; s1 *= s1;
  float s2 = e2 * e2; s2 *= s2;
  return iou - 0.5f * (dist + s1 + s2);
}

// K1: decoupled roles. Blocks [0,400): cell streaming (base obj term).
// Blocks [400,400+nact): anchor gather + SIoU. Critical path = max, not sum.
__global__ __launch_bounds__(TB)
void k1(const float* __restrict__ preds, const float* __restrict__ targets,
        int M, int* __restrict__ winner, float4* __restrict__ state4,
        float* __restrict__ partA_iou, float* __restrict__ partA_cnt,
        float* __restrict__ part_obj) {
  const int tid = threadIdx.x, bid = blockIdx.x;
  const int lane = tid & 63, wid = tid >> 6;
  __shared__ float sh0[4], sh1[4];

  if (bid < CELLB) {
    // ---- cells: one float4 per thread; tobj=0/factor=0.75 folded out ----
    int t = bid * TB + tid;
    int i0 = t * 4;
    int b = i0 / HW_;
    int r = i0 - b * HW_;                    // HW_ % 4 == 0
    float4 p4 = *reinterpret_cast<const float4*>(preds + (size_t)b * CC * HW_ + r);
    float objs = sl1(p4.x) + sl1(p4.y) + sl1(p4.z) + sl1(p4.w);
    float o = wave_sum(objs);
    if (lane == 0) sh0[wid] = o;
    __syncthreads();
    if (tid == 0) part_obj[bid] = sh0[0] + sh0[1] + sh0[2] + sh0[3];
  } else {
    // ---- anchors: decode + 6 gathers + SIoU + nll ----
    const int abid = bid - CELLB;
    const int t = abid * TB + tid;
    const int M4 = 4 * M;
    float iou_v = 0.f, mf = 0.f, pobj = 0.f, nllv = 0.f;
    int meta = 0;
    if (t < M4) {
      int mm = t % M, q = t / M;
      const float* t6 = targets + (size_t)mm * 6;
      int ab = (int)t6[0];
      int acls = (int)t6[1];
      float gx = t6[2] * (float)WW, gy = t6[3] * (float)HH;
      float gw = t6[4] * (float)WW, gh = t6[5] * (float)HH;
      int gi = (int)gx + (q & 1);
      int gj = (int)gy + (q >> 1);
      bool am = (gi >= 1) && (gi < WW) && (gj >= 1) && (gj < HH);
      if (am) {
        const float* p = preds + (size_t)ab * CC * HW_ + (size_t)gj * WW + gi;
        pobj = p[0];
        float p1 = p[(size_t)1 * HW_];
        float p2 = p[(size_t)2 * HW_];
        float p3 = p[(size_t)3 * HW_];
        float p4v = p[(size_t)4 * HW_];
        float pc = p[(size_t)(5 + acls) * HW_];
        float px = tanhf(p1) + (float)gi;
        float py = tanhf(p2) + (float)gj;
        float pw = (1.f / (1.f + expf(-p3))) * (float)WW;
        float ph = (1.f / (1.f + expf(-p4v))) * (float)HH;
        iou_v = siou(px, py, pw, ph, gx, gy, gw, gh);
        nllv = -logf(pc);
        mf = 1.f;
        int aidx = ab * HW_ + gj * WW + gi;
        winner[aidx] = -1;                   // scatter-init only cells used
        meta = 1 | (ab << 1) | (aidx << 5);  // aidx < 2^19 -> fits
      }
      state4[t] = make_float4(iou_v, pobj, nllv, __int_as_float(meta));
    }
    float s = wave_sum(iou_v), c = wave_sum(mf);
    if (lane == 0) { sh0[wid] = s; sh1[wid] = c; }
    __syncthreads();
    if (tid == 0) {
      partA_iou[abid] = sh0[0] + sh0[1] + sh0[2] + sh0[3];
      partA_cnt[abid] = sh1[0] + sh1[1] + sh1[2] + sh1[3];
    }
  }
}

// K2 (grid = nact, NO internal grid barrier): single filter pass using a
// TELESCOPING atomicMax correction. For each cell, the sequence of successful
// max-raises telescopes: sum of [A(new) - A(old)] = A(final winner). The
// nperb-dependent factor is deferred to finalize via per-batch buckets.
// Only block 0 spins (on per-block magic flags); all other blocks exit.
__global__ __launch_bounds__(TB)
void k2(const float4* __restrict__ state4, int* __restrict__ winner,
        const float* __restrict__ partA_iou, const float* __restrict__ partA_cnt,
        const float* __restrict__ part_obj, int* __restrict__ flags,
        int* __restrict__ hist64, float* __restrict__ corrA64,
        float4* __restrict__ partB, int M, int nact,
        float* __restrict__ out) {
  const int tid = threadIdx.x, bid = blockIdx.x;
  const int lane = tid & 63, wid = tid >> 6;
  const int M4 = 4 * M;

  __shared__ float r0[4], r1[4], r2[4], r3[4];
  __shared__ int hist[NN];
  __shared__ float corrA[NN];
  __shared__ float s_mean;
  if (tid < NN) { hist[tid] = 0; corrA[tid] = 0.f; }

  // ---- iou_mean: fixed-order reduce of the nact anchor partials ----
  {
    float si = 0.f, sc = 0.f;
    for (int i = tid; i < nact; i += TB) { si += partA_iou[i]; sc += partA_cnt[i]; }
    si = wave_sum(si); sc = wave_sum(sc);
    if (lane == 0) { r0[wid] = si; r1[wid] = sc; }
    __syncthreads();
    if (tid == 0)
      s_mean = (r0[0] + r0[1] + r0[2] + r0[3]) /
               fmaxf(r1[0] + r1[1] + r1[2] + r1[3], 1.f);
  }
  __syncthreads();
  const float iou_mean = s_mean;

  // ---- single filter pass with telescoping correction ----
  const int t = bid * TB + tid;
  float fc = 0.f, li = 0.f, nl = 0.f, corrB = 0.f;
  if (t < M4) {
    float4 s4 = state4[t];
    int meta = __float_as_int(s4.w);
    if ((meta & 1) && s4.x > iou_mean) {
      int b = (meta >> 1) & 15;
      fc = 1.f;
      li = 1.f - s4.x;
      nl = s4.z;
      atomicAdd(&hist[b], 1);
      int old = atomicMax(&winner[meta >> 5], t);
      if (old < t) {                 // we raised the max (old==-1 or smaller)
        float dA = sl1(s4.y - s4.x); // A(t) = sl1(pobj - iou_t)
        if (old >= 0) {
          float iou_old = state4[old].x;       // same cell -> same pobj
          dA -= sl1(s4.y - iou_old);
        } else {
          corrB = -0.75f * sl1(s4.y);          // first claimant pays B once
        }
        atomicAdd(&corrA[b], dA);
      }
    }
  }
  {
    float a = wave_sum(fc), b2 = wave_sum(li), d2 = wave_sum(nl), e2 = wave_sum(corrB);
    if (lane == 0) { r0[wid] = a; r1[wid] = b2; r2[wid] = d2; r3[wid] = e2; }
  }
  __syncthreads();
  if (tid == 0)
    partB[bid] = make_float4(r0[0] + r0[1] + r0[2] + r0[3],
                             r1[0] + r1[1] + r1[2] + r1[3],
                             r2[0] + r2[1] + r2[2] + r2[3],
                             r3[0] + r3[1] + r3[2] + r3[3]);
  if (tid < NN) {
    hist64[bid * NN + tid] = hist[tid];
    corrA64[bid * NN + tid] = corrA[tid];
  }
  __threadfence();                   // make this block's stores visible
  __syncthreads();
  if (tid == 0)
    __hip_atomic_store(&flags[bid], MAGICF, __ATOMIC_RELEASE,
                       __HIP_MEMORY_SCOPE_AGENT);
  if (bid != 0) return;

  // ---- finalize: block 0 only ----
  for (;;) {                         // wait for all nact flags
    int ok = 1;
    for (int i = tid; i < nact; i += TB)
      if (__hip_atomic_load(&flags[i], __ATOMIC_ACQUIRE,
                            __HIP_MEMORY_SCOPE_AGENT) != MAGICF) ok = 0;
    if (__syncthreads_and(ok)) break;
    __builtin_amdgcn_s_sleep(2);
  }

  // per-batch: nperb (int, deterministic) and corrA total (fixed order)
  float corr_b = 0.f;
  if (tid < NN) {
    int np = 0; float ca = 0.f;
    for (int j = 0; j < nact; ++j) {
      np += hist64[j * NN + tid];
      ca += corrA64[j * NN + tid];
    }
    if (np > 0) corr_b = ca * ((float)HW_ / (float)np * 0.25f);
  }
  // partB totals (lanes 0..nact-1 of waves, strided)
  float cf = 0.f, liou = 0.f, nll = 0.f, cB = 0.f;
  for (int i = tid; i < nact; i += TB) {
    float4 pb = partB[i];
    cf += pb.x; liou += pb.y; nll += pb.z; cB += pb.w;
  }
  // obj_base from 400 cell partials
  float ob = 0.f;
  for (int i = tid; i < CELLB; i += TB) ob += part_obj[i];

  corr_b = wave_sum(corr_b); cf = wave_sum(cf); liou = wave_sum(liou);
  nll = wave_sum(nll); cB = wave_sum(cB); ob = wave_sum(ob);
  if (lane == 0) { r0[wid] = corr_b + cB; r1[wid] = cf; r2[wid] = liou + nll * 1e-30f; }
  // (pack: need 5 values across 4 waves; use two shared passes instead)
  __syncthreads();
  __shared__ float f0[4], f1[4], f2[4], f3[4], f4[4];
  if (lane == 0) { f0[wid] = corr_b + cB; f1[wid] = cf; f2[wid] = liou;
                   f3[wid] = nll; f4[wid] = ob; }
  __syncthreads();
  if (tid == 0) {
    float corr = f0[0] + f0[1] + f0[2] + f0[3];
    float cft  = f1[0] + f1[1] + f1[2] + f1[3];
    float lit  = f2[0] + f2[1] + f2[2] + f2[3];
    float nlt  = f3[0] + f3[1] + f3[2] + f3[3];
    float obt  = f4[0] + f4[1] + f4[2] + f4[3];
    float cff = fmaxf(cft, 1.f);
    float iou_loss = lit / cff;
    float cls_loss = nlt / cff;
    float obj_loss = (0.75f * obt + corr) / (float)NHW;
    out[0] = iou_loss;
    out[1] = obj_loss;
    out[2] = cls_loss;
    out[3] = iou_loss * 8.f + obj_loss * 16.f + cls_loss;
  }
  // clear flags for the next graph replay (all other blocks have exited:
  // their flag store was their final memory operation)
  __syncthreads();
  for (int i = tid; i < nact; i += TB) flags[i] = 0;
}

extern "C" void kernel_launch(void* const* d_in, const int* in_sizes, int n_in,
                              void* d_out, int out_size, void* d_ws, size_t ws_size,
                              hipStream_t stream) {
  const float* preds = (const float*)d_in[0];
  const float* targets = (const float*)d_in[1];
  int M = in_sizes[1] / 6;             // 4096
  int M4 = 4 * M;                      // 16384
  int nact = (M4 + TB - 1) / TB;       // 64 anchor blocks

  char* ws = (char*)d_ws;
  size_t off = 0;
  float4* state4 = (float4*)(ws + off);   off += (size_t)M4 * 16;       // 256 KB
  int* winner = (int*)(ws + off);         off += (size_t)NHW * 4;       // 1.6 MB
  float* partA_iou = (float*)(ws + off);  off += ((size_t)nact * 4 + 255) & ~(size_t)255;
  float* partA_cnt = (float*)(ws + off);  off += ((size_t)nact * 4 + 255) & ~(size_t)255;
  float* part_obj = (float*)(ws + off);   off += ((size_t)CELLB * 4 + 255) & ~(size_t)255;
  int* flags = (int*)(ws + off);          off += ((size_t)nact * 4 + 255) & ~(size_t)255;
  int* hist64 = (int*)(ws + off);         off += ((size_t)nact * NN * 4 + 255) & ~(size_t)255;
  float* corrA64 = (float*)(ws + off);    off += ((size_t)nact * NN * 4 + 255) & ~(size_t)255;
  float4* partB = (float4*)(ws + off);    off += (size_t)nact * 16;

  k1<<<CELLB + nact, TB, 0, stream>>>(preds, targets, M, winner, state4,
                                      partA_iou, partA_cnt, part_obj);
  k2<<<nact, TB, 0, stream>>>(state4, winner, partA_iou, partA_cnt, part_obj,
                              flags, hist64, corrA64, partB, M, nact,
                              (float*)d_out);
}